// Round 5
// baseline (99.991 us; speedup 1.0000x reference)
//
#include <hip/hip_runtime.h>
#include <hip/hip_bf16.h>

#define N_    16
#define IC_   512
#define OC_   512
#define SDIM_ 512
#define H_    32
#define W_    32
#define HW_   1024

#define FC_SCALER 0.04419417382415922f          /* 1/sqrt(512) */
#define WS_       0.014731391274719738f         /* 1/sqrt(4608) */
#define WS2_      (1.0f/4608.0f)

typedef __attribute__((__ext_vector_type__(8)))  __bf16 bf16x8;
typedef __attribute__((__ext_vector_type__(16))) float  f32x16;
typedef __attribute__((__ext_vector_type__(4)))  int    i32x4;

typedef __attribute__((address_space(1))) const unsigned int GInt;
typedef __attribute__((address_space(3))) unsigned int LInt;

#define WAIT3()  asm volatile("s_waitcnt vmcnt(3)"  ::: "memory")
#define WAIT8()  asm volatile("s_waitcnt vmcnt(8)"  ::: "memory")
#define WAIT0()  asm volatile("s_waitcnt vmcnt(0)"  ::: "memory")

__device__ __forceinline__ unsigned short f2bf(float f) {
    unsigned int u = __builtin_bit_cast(unsigned int, f);
    unsigned int r = (u + 0x7FFFu + ((u >> 16) & 1u)) >> 16;
    return (unsigned short)r;
}

// ---------------- K1: mod[n][c] = style[n]·fcw[c]*FC_SCALER + fcb[c] + 1 ----------------
__global__ void k_mod(const float* __restrict__ style, const float* __restrict__ fcw,
                      const float* __restrict__ fcb, float* __restrict__ mod) {
    int gid = blockIdx.x * blockDim.x + threadIdx.x;
    int wid = gid >> 6, lane = gid & 63;
    if (wid >= N_ * IC_) return;
    int n = wid >> 9, c = wid & 511;
    const float4* sp = (const float4*)(style + n * SDIM_);
    const float4* wp = (const float4*)(fcw + (size_t)c * SDIM_);
    float acc = 0.f;
    for (int i = lane; i < SDIM_ / 4; i += 64) {
        float4 a = sp[i], b = wp[i];
        acc += a.x*b.x + a.y*b.y + a.z*b.z + a.w*b.w;
    }
#pragma unroll
    for (int off = 32; off; off >>= 1) acc += __shfl_xor(acc, off);
    if (lane == 0) mod[wid] = acc * FC_SCALER + fcb[c] + 1.0f;
}

// ---------------- K2: wt k-major: [tap][og8][icc16][ks4][ocl64][8ic] --------------------
__global__ void k_wprep(const float* __restrict__ w, unsigned short* __restrict__ wt,
                        float* __restrict__ wsq) {
    int tid = blockIdx.x * blockDim.x + threadIdx.x;   // 0 .. OC*IC-1
    int oc = tid >> 9, ic = tid & 511;
    int og = oc >> 6, ocl = oc & 63;
    int icc = ic >> 5, ks = (ic >> 3) & 3, i8 = ic & 7;
    float s = 0.f;
#pragma unroll
    for (int t = 0; t < 9; t++) {
        float v = w[(size_t)tid * 9 + t];
        s += v * v;
        size_t off = (((size_t)t * 8 + og) * 16 + icc) * 2048
                   + (size_t)ks * 512 + ocl * 8 + i8;
        wt[off] = f2bf(v);
    }
    wsq[tid] = s;
}

// ---------------- K3: demod_ws[n][oc] = WS * rsqrt(WS2*sum_ic mod^2*wsq + 1e-8) ---------
__global__ void k_demod(const float* __restrict__ mod, const float* __restrict__ wsq,
                        float* __restrict__ demod_ws) {
    int gid = blockIdx.x * blockDim.x + threadIdx.x;
    int wid = gid >> 6, lane = gid & 63;
    if (wid >= N_ * OC_) return;
    int n = wid >> 9, oc = wid & 511;
    const float4* mp = (const float4*)(mod + n * IC_);
    const float4* qp = (const float4*)(wsq + (size_t)oc * IC_);
    float acc = 0.f;
    for (int i = lane; i < IC_ / 4; i += 64) {
        float4 m = mp[i], q = qp[i];
        acc += m.x*m.x*q.x + m.y*m.y*q.y + m.z*m.z*q.z + m.w*m.w*q.w;
    }
#pragma unroll
    for (int off = 32; off; off >>= 1) acc += __shfl_xor(acc, off);
    if (lane == 0) {
        float s = WS2_ * acc + 1e-8f;
        demod_ws[wid] = WS_ / sqrtf(s);
    }
}

// ---------------- K4: xm k-major: [n][icc16][y32][ks4][x32][8ic] (bf16) -----------------
__global__ void k_premod(const float* __restrict__ x, const float* __restrict__ mod,
                         unsigned short* __restrict__ xm) {
    __shared__ __align__(16) unsigned short t_lds[64][80];
    int bx = blockIdx.x;                 // n(16) * hwt(16) * ict(8)
    int n = bx >> 7, hwt = (bx >> 3) & 15, ict = bx & 7;
    int hw0 = hwt * 64, ic0 = ict * 64;
    int tid = threadIdx.x, lane = tid & 63, ty = tid >> 6;
#pragma unroll
    for (int jj = 0; jj < 16; jj++) {
        int icl = ty * 16 + jj;
        float v = x[(size_t)(n * IC_ + ic0 + icl) * HW_ + hw0 + lane]
                  * mod[n * IC_ + ic0 + icl];
        t_lds[lane][icl] = f2bf(v);
    }
    __syncthreads();
    int xcol = tid & 31, ks64 = tid >> 5;           // ks64 0..7 within the 64-ic block
    int icc = ict * 2 + (ks64 >> 2), ks = ks64 & 3;
#pragma unroll
    for (int rep = 0; rep < 2; rep++) {
        int hwl = rep * 32 + xcol;
        i32x4 v = *(const i32x4*)&t_lds[hwl][ks64 * 8];
        int y = (hw0 >> 5) + rep;
        size_t off = ((((size_t)n * 16 + icc) * 32 + y) * 4 + ks) * 256 + xcol * 8;
        *(i32x4*)(xm + off) = v;
    }
}

// ---------------- K5: implicit-GEMM conv, bf16 MFMA 32x32x16 ----------------------------
// grid 512 (n-major XCD swizzle), block 256 thr = 4 waves (kh2 x wc2) -> 2 blocks/CU.
// Block tile 64oc x 256sp (8 rows) x 32ic-chunk; wave 64oc x 128sp (4 rows) x 16ic.
// dx-major phases; 3 weight sets (2-phase flight) + x dbuf (3-phase flight).
// Waits: vmcnt(3) @p0, vmcnt(8) @p1/p2 -- never drain to 0 in the loop.
__global__ __launch_bounds__(256, 2)
void k_conv(const unsigned short* __restrict__ xm, const unsigned short* __restrict__ wt,
            const float* __restrict__ demod_ws, float* __restrict__ out) {
    __shared__ __align__(16) char smem[79136];
    // xt: 2 bufs x 10 rows x 1024 shorts = 40960 B @0
    // wb: 3 sets x 3 taps x 2048 shorts  = 36864 B @40960
    // trash @77824 (1KB); zslot @78848 (32B); s_demod @78880 (256B)
    unsigned short* xt0     = (unsigned short*)(smem);
    unsigned short* wb0     = (unsigned short*)(smem + 40960);
    unsigned short* trash   = (unsigned short*)(smem + 77824);
    float*          zslot   = (float*)(smem + 78848);
    float*          s_demod = (float*)(smem + 78880);

    int bx = blockIdx.x;
    // n-major XCD grouping: XCD (bx%8) hosts 2 n's; octg/spt spread within XCD.
    int x8 = bx & 7, j = bx >> 3;               // j 0..63
    int n = x8 * 2 + (j >> 5);
    int rem = j & 31;
    int octg = rem >> 2, spt = rem & 3;
    int oc0 = octg * 64, y0 = spt * 8;

    int tid = threadIdx.x, lane = tid & 63, wid = tid >> 6;
    int l31 = lane & 31, lhi = lane >> 5;
    int wc = wid & 1, kh = wid >> 1;

    // scalar prologue load FIRST; fence so its implicit vmcnt(0) precedes staging issues
    if (tid < 64) s_demod[tid] = demod_ws[n * OC_ + oc0 + tid];
    __builtin_amdgcn_sched_barrier(0);

    if (tid == 0) { i32x4 z = {}; *(i32x4*)zslot = z; }
    // pre-zero OOB halo rows of both x bufs (their loads are routed to trash)
    if (spt == 0 && tid < 128) {
        i32x4 z = {};
        *(i32x4*)&xt0[tid * 8] = z;                       // buf0 row 0
        *(i32x4*)&xt0[10240 + tid * 8] = z;               // buf1 row 0
    }
    if (spt == 3 && tid < 128) {
        i32x4 z = {};
        *(i32x4*)&xt0[9 * 1024 + tid * 8] = z;            // buf0 row 9
        *(i32x4*)&xt0[10240 + 9 * 1024 + tid * 8] = z;    // buf1 row 9
    }

    const unsigned short* xsrc_n = xm + (size_t)n * (16 * 32 * 1024);

    // x tile: 10 rows x [4ks][32col][8ic] = 20KB = 20 chunks of 1KB, 5 per wave
    auto stage_x = [&](int buf, int icc) {
#pragma unroll
        for (int k = 0; k < 5; k++) {
            int c = wid + k * 4;                 // 0..19
            int rr = c >> 1, hh = c & 1;
            int y = y0 - 1 + rr;
            bool oob = ((unsigned)y >= 32u) | (icc >= 16);
            int yc = y < 0 ? 0 : (y > 31 ? 31 : y);
            int iccc = icc & 15;
            const unsigned short* g =
                xsrc_n + ((size_t)iccc * 32 + yc) * 1024 + hh * 512 + lane * 8;
            unsigned short* l = oob ? trash
                                    : xt0 + buf * 10240 + rr * 1024 + hh * 512;
            __builtin_amdgcn_global_load_lds((GInt*)g, (LInt*)l, 16, 0, 0);
        }
    };
    // weight set for global phase g2: 3 taps (dy) x 2048 shorts; wave does quarter wid
    auto stage_w = [&](int g2) {
        int gc = g2 < 48 ? g2 : 47;
        int icc2 = gc / 3, p2 = gc % 3;
        bool oob = g2 >= 48;
#pragma unroll
        for (int k = 0; k < 3; k++) {
            int tap = k * 3 + p2;
            const unsigned short* g =
                wt + (((size_t)tap * 8 + octg) * 16 + icc2) * 2048 + wid * 512 + lane * 8;
            unsigned short* l = oob ? trash
                                    : wb0 + (g2 % 3) * 6144 + k * 2048 + wid * 512;
            __builtin_amdgcn_global_load_lds((GInt*)g, (LInt*)l, 16, 0, 0);
        }
    };

    f32x16 acc[2][4] = {};

    stage_x(0, 0);
    stage_w(0);
    stage_w(1);
    asm volatile("s_waitcnt lgkmcnt(0)" ::: "memory");   // zero-fills + s_demod visible

    int xb = 0;
    int kso = kh * 2 + lhi;                              // per-lane k-slot (8ic)
#pragma unroll 1
    for (int icc = 0; icc < 16; icc++) {
#pragma unroll 1
        for (int p = 0; p < 3; p++) {
            int g = icc * 3 + p;
            // wait: w(g) issued 2 phases ago; @p0 also x(icc) issued 3 phases ago
            if (p == 0) WAIT3(); else WAIT8();
            __builtin_amdgcn_s_barrier();
            // issue w(g+2); @p0 also x(icc+1)
            stage_w(g + 2);
            if (p == 0) stage_x(xb ^ 1, icc + 1);

            // compute: 6 x-row frags once, reuse across dy and fs
            const unsigned short* xtb = xt0 + xb * 10240;
            const unsigned short* wbp = wb0 + (g % 3) * 6144;
            int col = l31 + p - 1;
            bool oobc = (unsigned)col >= 32u;
            bf16x8 r6[6];
#pragma unroll
            for (int jj = 0; jj < 6; jj++) {
                int rr = wc * 4 + jj;
                const unsigned short* src = oobc ? (const unsigned short*)zslot
                    : xtb + rr * 1024 + kso * 256 + col * 8;
                r6[jj] = *(const bf16x8*)src;
            }
#pragma unroll
            for (int dy = 0; dy < 3; dy++) {
                bf16x8 af0 = *(const bf16x8*)(wbp + dy * 2048 + kso * 512 + l31 * 8);
                bf16x8 af1 = *(const bf16x8*)(wbp + dy * 2048 + kso * 512 + (32 + l31) * 8);
                __builtin_amdgcn_s_setprio(1);
#pragma unroll
                for (int fs = 0; fs < 4; fs++)
                    acc[0][fs] = __builtin_amdgcn_mfma_f32_32x32x16_bf16(
                        af0, r6[fs + dy], acc[0][fs], 0, 0, 0);
#pragma unroll
                for (int fs = 0; fs < 4; fs++)
                    acc[1][fs] = __builtin_amdgcn_mfma_f32_32x32x16_bf16(
                        af1, r6[fs + dy], acc[1][fs], 0, 0, 0);
                __builtin_amdgcn_s_setprio(0);
            }
        }
        xb ^= 1;
    }

    // ---- epilogue: combine kh halves via LDS exchange, scale, store fp32 NCHW ----
    WAIT0();                                  // drain trailing trash loads
    __syncthreads();
    float* exch = (float*)smem;               // 64KB, aliases xt+wb (no pending DMA there)
    if (kh == 1) {
#pragma unroll
        for (int fo = 0; fo < 2; fo++)
#pragma unroll
            for (int fs = 0; fs < 4; fs++)
#pragma unroll
                for (int rg = 0; rg < 16; rg++)
                    exch[(((wc * 2 + fo) * 4 + fs) * 16 + rg) * 64 + lane] = acc[fo][fs][rg];
    }
    __syncthreads();
    if (kh == 0) {
#pragma unroll
        for (int fo = 0; fo < 2; fo++) {
#pragma unroll
            for (int fs = 0; fs < 4; fs++) {
                int y = y0 + wc * 4 + fs;
#pragma unroll
                for (int rg = 0; rg < 16; rg++) {
                    int row = (rg & 3) + 8 * (rg >> 2) + 4 * lhi;
                    int ocl = fo * 32 + row;
                    float v = acc[fo][fs][rg]
                            + exch[(((wc * 2 + fo) * 4 + fs) * 16 + rg) * 64 + lane];
                    v *= s_demod[ocl];
                    out[((size_t)(n * OC_ + oc0 + ocl) * H_ + y) * W_ + l31] = v;
                }
            }
        }
    }
}

extern "C" void kernel_launch(void* const* d_in, const int* in_sizes, int n_in,
                              void* d_out, int out_size, void* d_ws, size_t ws_size,
                              hipStream_t stream) {
    const float* x      = (const float*)d_in[0];
    const float* style  = (const float*)d_in[1];
    const float* weight = (const float*)d_in[2];
    const float* fcw    = (const float*)d_in[3];
    const float* fcb    = (const float*)d_in[4];
    float* out = (float*)d_out;

    char* ws = (char*)d_ws;
    float*          mod   = (float*)ws;                          // 32 KB
    float*          demod = (float*)(ws + 32768);                // 32 KB
    float*          wsq   = (float*)(ws + 65536);                // 1 MB
    unsigned short* wtb   = (unsigned short*)(ws + 65536 + 1048576);           // 4.5 MB
    unsigned short* xmb   = (unsigned short*)(ws + 65536 + 1048576 + 4718592); // 16 MB

    k_mod   <<<2048, 256, 0, stream>>>(style, fcw, fcb, mod);
    k_wprep <<<1024, 256, 0, stream>>>(weight, wtb, wsq);
    k_demod <<<2048, 256, 0, stream>>>(mod, wsq, demod);
    k_premod<<<2048, 256, 0, stream>>>(x, mod, xmb);
    k_conv  <<<512,  256, 0, stream>>>(xmb, wtb, demod, out);
}

// Round 6
// 99.706 us; speedup vs baseline: 1.0029x; 1.0029x over previous
//
#include <hip/hip_runtime.h>
#include <hip/hip_bf16.h>

#define N_    16
#define IC_   512
#define OC_   512
#define SDIM_ 512
#define H_    32
#define W_    32
#define HW_   1024

#define FC_SCALER 0.04419417382415922f          /* 1/sqrt(512) */
#define WS_       0.014731391274719738f         /* 1/sqrt(4608) */
#define WS2_      (1.0f/4608.0f)

typedef __attribute__((__ext_vector_type__(8)))  __bf16 bf16x8;
typedef __attribute__((__ext_vector_type__(16))) float  f32x16;
typedef __attribute__((__ext_vector_type__(4)))  int    i32x4;

typedef __attribute__((address_space(1))) const unsigned int GInt;
typedef __attribute__((address_space(3))) unsigned int LInt;

#define WAIT3()  asm volatile("s_waitcnt vmcnt(3)"  ::: "memory")
#define WAIT43() asm volatile("s_waitcnt vmcnt(43)" ::: "memory")
#define WAIT46() asm volatile("s_waitcnt vmcnt(46)" ::: "memory")
#define WAIT0()  asm volatile("s_waitcnt vmcnt(0)"  ::: "memory")
#define LGKM0()  asm volatile("s_waitcnt lgkmcnt(0)" ::: "memory")
#define SB()     __builtin_amdgcn_sched_barrier(0)

__device__ __forceinline__ unsigned short f2bf(float f) {
    unsigned int u = __builtin_bit_cast(unsigned int, f);
    unsigned int r = (u + 0x7FFFu + ((u >> 16) & 1u)) >> 16;
    return (unsigned short)r;
}

// ---------------- K1: mod[n][c] = style[n]·fcw[c]*FC_SCALER + fcb[c] + 1 ----------------
__global__ void k_mod(const float* __restrict__ style, const float* __restrict__ fcw,
                      const float* __restrict__ fcb, float* __restrict__ mod) {
    int gid = blockIdx.x * blockDim.x + threadIdx.x;
    int wid = gid >> 6, lane = gid & 63;
    if (wid >= N_ * IC_) return;
    int n = wid >> 9, c = wid & 511;
    const float4* sp = (const float4*)(style + n * SDIM_);
    const float4* wp = (const float4*)(fcw + (size_t)c * SDIM_);
    float acc = 0.f;
    for (int i = lane; i < SDIM_ / 4; i += 64) {
        float4 a = sp[i], b = wp[i];
        acc += a.x*b.x + a.y*b.y + a.z*b.z + a.w*b.w;
    }
#pragma unroll
    for (int off = 32; off; off >>= 1) acc += __shfl_xor(acc, off);
    if (lane == 0) mod[wid] = acc * FC_SCALER + fcb[c] + 1.0f;
}

// ---------------- K2: wt k-major: [tap][og8][icc16][ks4][ocl64][8ic] --------------------
__global__ void k_wprep(const float* __restrict__ w, unsigned short* __restrict__ wt,
                        float* __restrict__ wsq) {
    int tid = blockIdx.x * blockDim.x + threadIdx.x;   // 0 .. OC*IC-1
    int oc = tid >> 9, ic = tid & 511;
    int og = oc >> 6, ocl = oc & 63;
    int icc = ic >> 5, ks = (ic >> 3) & 3, i8 = ic & 7;
    float s = 0.f;
#pragma unroll
    for (int t = 0; t < 9; t++) {
        float v = w[(size_t)tid * 9 + t];
        s += v * v;
        size_t off = (((size_t)t * 8 + og) * 16 + icc) * 2048
                   + (size_t)ks * 512 + ocl * 8 + i8;
        wt[off] = f2bf(v);
    }
    wsq[tid] = s;
}

// ---------------- K3: demod_ws[n][oc] = WS * rsqrt(WS2*sum_ic mod^2*wsq + 1e-8) ---------
__global__ void k_demod(const float* __restrict__ mod, const float* __restrict__ wsq,
                        float* __restrict__ demod_ws) {
    int gid = blockIdx.x * blockDim.x + threadIdx.x;
    int wid = gid >> 6, lane = gid & 63;
    if (wid >= N_ * OC_) return;
    int n = wid >> 9, oc = wid & 511;
    const float4* mp = (const float4*)(mod + n * IC_);
    const float4* qp = (const float4*)(wsq + (size_t)oc * IC_);
    float acc = 0.f;
    for (int i = lane; i < IC_ / 4; i += 64) {
        float4 m = mp[i], q = qp[i];
        acc += m.x*m.x*q.x + m.y*m.y*q.y + m.z*m.z*q.z + m.w*m.w*q.w;
    }
#pragma unroll
    for (int off = 32; off; off >>= 1) acc += __shfl_xor(acc, off);
    if (lane == 0) {
        float s = WS2_ * acc + 1e-8f;
        demod_ws[wid] = WS_ / sqrtf(s);
    }
}

// ---------------- K4 (fused conv): implicit-GEMM, premod fused into x staging -----------
// grid 512 (n-major XCD swizzle), block 256 thr = 4 waves (kh2 x wc2), 2 blocks/CU.
// Block tile 64oc x 256sp (8 rows) x 32ic-chunk; wave 64oc x 128sp (4 rows) x 16ic.
// x staged fp32 global -> regs (40 dw/thread) -> *mod -> cvt_pk bf16 -> ds_write_b128.
// dx-major phases; 3 weight LDS sets (2-phase flight). Waits: p0 vmcnt(3), p1/p2 vmcnt(43).
__global__ __launch_bounds__(256, 2)
void k_conv(const float* __restrict__ x, const float* __restrict__ mod,
            const unsigned short* __restrict__ wt,
            const float* __restrict__ demod_ws, float* __restrict__ out) {
    __shared__ __align__(16) char smem[81184];
    // xt[2] @0 (2x20480), wb[3] @40960 (3x12288=36864), trash @77824 (1024),
    // zslot @78848 (32), s_demod @78880 (256), mod_lds @79136 (2048)
    unsigned short* xt0     = (unsigned short*)(smem);
    unsigned short* wb0     = (unsigned short*)(smem + 40960);
    unsigned short* trash   = (unsigned short*)(smem + 77824);
    float*          zslot   = (float*)(smem + 78848);
    float*          s_demod = (float*)(smem + 78880);
    float*          mod_lds = (float*)(smem + 79136);

    int bx = blockIdx.x;
    // n-major XCD grouping: XCD (bx%8) hosts 2 n's -> x L2 locality
    int x8 = bx & 7, jj = bx >> 3;              // jj 0..63
    int n = x8 * 2 + (jj >> 5);
    int rem = jj & 31;
    int octg = rem >> 2, spt = rem & 3;
    int oc0 = octg * 64, y0 = spt * 8;

    int tid = threadIdx.x, lane = tid & 63, wid = tid >> 6;
    int l31 = lane & 31, lhi = lane >> 5;
    int wc = wid & 1, kh = wid >> 1;

    // scalar prologue staging first; pin with sched_barrier
    if (tid < 64) s_demod[tid] = demod_ws[n * OC_ + oc0 + tid];
    if (tid < 128) ((float4*)mod_lds)[tid] = ((const float4*)(mod + n * IC_))[tid];
    if (tid == 0) { i32x4 z = {}; *(i32x4*)zslot = z; }
    SB();

    const float* xsrc = x + (size_t)n * IC_ * HW_;

    // ---- x reg staging: thread handles (ks=wid, col=l31), rows rr = lhi+2k, 8 ic each --
    float xr[5][8];
    auto stage_xregs = [&](int icc) {
#pragma unroll
        for (int k = 0; k < 5; k++) {
            int rr = lhi + 2 * k;
            int y = y0 - 1 + rr;
            int yc = y < 0 ? 0 : (y > 31 ? 31 : y);
            const float* base = xsrc + ((size_t)(icc * 32 + wid * 8)) * HW_ + yc * 32 + l31;
#pragma unroll
            for (int i = 0; i < 8; i++) xr[k][i] = base[(size_t)i * HW_];
        }
    };
    // cvt xr (holding x(icct)) -> xt[buf]; oob rows write zeros
    auto cvt_store = [&](int icct, int buf) {
        int mi = (icct & 15) * 32 + wid * 8;
        float4 mA = *(const float4*)&mod_lds[mi];
        float4 mB = *(const float4*)&mod_lds[mi + 4];
#pragma unroll
        for (int k = 0; k < 5; k++) {
            int rr = lhi + 2 * k;
            int y = y0 - 1 + rr;
            bool oob = (unsigned)y >= 32u;
            unsigned r0 = 0, r1 = 0, r2 = 0, r3 = 0;
            if (!oob) {
                float f0 = xr[k][0]*mA.x, f1 = xr[k][1]*mA.y;
                float f2 = xr[k][2]*mA.z, f3 = xr[k][3]*mA.w;
                float f4 = xr[k][4]*mB.x, f5 = xr[k][5]*mB.y;
                float f6 = xr[k][6]*mB.z, f7 = xr[k][7]*mB.w;
                asm("v_cvt_pk_bf16_f32 %0, %1, %2" : "=v"(r0) : "v"(f0), "v"(f1));
                asm("v_cvt_pk_bf16_f32 %0, %1, %2" : "=v"(r1) : "v"(f2), "v"(f3));
                asm("v_cvt_pk_bf16_f32 %0, %1, %2" : "=v"(r2) : "v"(f4), "v"(f5));
                asm("v_cvt_pk_bf16_f32 %0, %1, %2" : "=v"(r3) : "v"(f6), "v"(f7));
            }
            i32x4 v = { (int)r0, (int)r1, (int)r2, (int)r3 };
            *(i32x4*)(xt0 + buf * 10240 + rr * 1024 + wid * 256 + l31 * 8) = v;
        }
    };
    // weight set for global phase g2: 3 taps (dy) x 2048 shorts; wave loads its quarter
    auto stage_w = [&](int g2) {
        int gc = g2 < 48 ? g2 : 47;
        int icc2 = gc / 3, p2 = gc % 3;
        bool oob = g2 >= 48;
#pragma unroll
        for (int k = 0; k < 3; k++) {
            int tap = k * 3 + p2;
            const unsigned short* g =
                wt + (((size_t)tap * 8 + octg) * 16 + icc2) * 2048 + wid * 512 + lane * 8;
            unsigned short* l = oob ? trash
                                    : wb0 + (g2 % 3) * 6144 + k * 2048 + wid * 512;
            __builtin_amdgcn_global_load_lds((GInt*)g, (LInt*)l, 16, 0, 0);
        }
    };

    f32x16 acc[2][4] = {};
    int xb = 0;
    int kso = kh * 2 + lhi;                              // per-lane compute k-slot

    auto compute = [&](int p, const unsigned short* wbp) {
        const unsigned short* xtb = xt0 + xb * 10240;
        int col = l31 + p - 1;
        bool oobc = (unsigned)col >= 32u;
        bf16x8 r6[6];
#pragma unroll
        for (int j = 0; j < 6; j++) {
            int rr = wc * 4 + j;
            const unsigned short* src = oobc ? (const unsigned short*)zslot
                : xtb + rr * 1024 + kso * 256 + col * 8;
            r6[j] = *(const bf16x8*)src;
        }
#pragma unroll
        for (int dy = 0; dy < 3; dy++) {
            bf16x8 af0 = *(const bf16x8*)(wbp + dy * 2048 + kso * 512 + l31 * 8);
            bf16x8 af1 = *(const bf16x8*)(wbp + dy * 2048 + kso * 512 + (32 + l31) * 8);
            __builtin_amdgcn_s_setprio(1);
#pragma unroll
            for (int fs = 0; fs < 4; fs++)
                acc[0][fs] = __builtin_amdgcn_mfma_f32_32x32x16_bf16(
                    af0, r6[fs + dy], acc[0][fs], 0, 0, 0);
#pragma unroll
            for (int fs = 0; fs < 4; fs++)
                acc[1][fs] = __builtin_amdgcn_mfma_f32_32x32x16_bf16(
                    af1, r6[fs + dy], acc[1][fs], 0, 0, 0);
            __builtin_amdgcn_s_setprio(0);
        }
    };

    // ---- prologue: order [x0][x1][w0][w1] so steady-state waits hold from icc=0 ----
    stage_xregs(0); SB();
    // park x0 in temp regs: cvt needs x0 now, xr will be reloaded with x1
    float x0r[5][8];
#pragma unroll
    for (int k = 0; k < 5; k++)
#pragma unroll
        for (int i = 0; i < 8; i++) x0r[k][i] = xr[k][i];
    stage_xregs(1); SB();
    stage_w(0); stage_w(1); SB();
    WAIT46();                     // x0 landed (x1,w0,w1 in flight... x1=40,w=6 -> 46)
    LGKM0();
    __builtin_amdgcn_s_barrier(); // mod_lds visible to all threads
    {   // cvt x0 -> xt[0] using parked regs
        int mi = 0 * 32 + wid * 8;
        float4 mA = *(const float4*)&mod_lds[mi];
        float4 mB = *(const float4*)&mod_lds[mi + 4];
#pragma unroll
        for (int k = 0; k < 5; k++) {
            int rr = lhi + 2 * k;
            int y = y0 - 1 + rr;
            bool oob = (unsigned)y >= 32u;
            unsigned r0 = 0, r1 = 0, r2 = 0, r3 = 0;
            if (!oob) {
                float f0 = x0r[k][0]*mA.x, f1 = x0r[k][1]*mA.y;
                float f2 = x0r[k][2]*mA.z, f3 = x0r[k][3]*mA.w;
                float f4 = x0r[k][4]*mB.x, f5 = x0r[k][5]*mB.y;
                float f6 = x0r[k][6]*mB.z, f7 = x0r[k][7]*mB.w;
                asm("v_cvt_pk_bf16_f32 %0, %1, %2" : "=v"(r0) : "v"(f0), "v"(f1));
                asm("v_cvt_pk_bf16_f32 %0, %1, %2" : "=v"(r1) : "v"(f2), "v"(f3));
                asm("v_cvt_pk_bf16_f32 %0, %1, %2" : "=v"(r2) : "v"(f4), "v"(f5));
                asm("v_cvt_pk_bf16_f32 %0, %1, %2" : "=v"(r3) : "v"(f6), "v"(f7));
            }
            i32x4 v = { (int)r0, (int)r1, (int)r2, (int)r3 };
            *(i32x4*)(xt0 + rr * 1024 + wid * 256 + l31 * 8) = v;
        }
    }
    SB();

#pragma unroll 1
    for (int icc = 0; icc < 16; icc++) {
        int g0 = icc * 3;
        // ---------------- p0 ----------------
        WAIT3();                  // w(g0) + x(icc+1) landed
        LGKM0();
        __builtin_amdgcn_s_barrier();
        cvt_store(icc + 1, xb ^ 1);
        SB();
        stage_w(g0 + 2);
        SB();
        stage_xregs((icc + 2) & 15);
        SB();
        compute(0, wb0 + (g0 % 3) * 6144);
        // ---------------- p1 ----------------
        WAIT43();                 // w(g0+1) landed
        LGKM0();
        __builtin_amdgcn_s_barrier();
        stage_w(g0 + 3);
        SB();
        compute(1, wb0 + ((g0 + 1) % 3) * 6144);
        // ---------------- p2 ----------------
        WAIT43();                 // w(g0+2) landed
        LGKM0();
        __builtin_amdgcn_s_barrier();
        stage_w(g0 + 4);
        SB();
        compute(2, wb0 + ((g0 + 2) % 3) * 6144);
        xb ^= 1;
    }

    // ---- epilogue: combine kh halves via LDS exchange, scale, store fp32 NCHW ----
    WAIT0();
    __syncthreads();
    float* exch = (float*)smem;               // aliases xt+wb (drained)
    if (kh == 1) {
#pragma unroll
        for (int fo = 0; fo < 2; fo++)
#pragma unroll
            for (int fs = 0; fs < 4; fs++)
#pragma unroll
                for (int rg = 0; rg < 16; rg++)
                    exch[(((wc * 2 + fo) * 4 + fs) * 16 + rg) * 64 + lane] = acc[fo][fs][rg];
    }
    __syncthreads();
    if (kh == 0) {
#pragma unroll
        for (int fo = 0; fo < 2; fo++) {
#pragma unroll
            for (int fs = 0; fs < 4; fs++) {
                int y = y0 + wc * 4 + fs;
#pragma unroll
                for (int rg = 0; rg < 16; rg++) {
                    int row = (rg & 3) + 8 * (rg >> 2) + 4 * lhi;
                    int ocl = fo * 32 + row;
                    float v = acc[fo][fs][rg]
                            + exch[(((wc * 2 + fo) * 4 + fs) * 16 + rg) * 64 + lane];
                    v *= s_demod[ocl];
                    out[((size_t)(n * OC_ + oc0 + ocl) * H_ + y) * W_ + l31] = v;
                }
            }
        }
    }
}

extern "C" void kernel_launch(void* const* d_in, const int* in_sizes, int n_in,
                              void* d_out, int out_size, void* d_ws, size_t ws_size,
                              hipStream_t stream) {
    const float* x      = (const float*)d_in[0];
    const float* style  = (const float*)d_in[1];
    const float* weight = (const float*)d_in[2];
    const float* fcw    = (const float*)d_in[3];
    const float* fcb    = (const float*)d_in[4];
    float* out = (float*)d_out;

    char* ws = (char*)d_ws;
    float*          mod   = (float*)ws;                          // 32 KB
    float*          demod = (float*)(ws + 32768);                // 32 KB
    float*          wsq   = (float*)(ws + 65536);                // 1 MB
    unsigned short* wtb   = (unsigned short*)(ws + 65536 + 1048576);           // 4.5 MB

    k_mod   <<<2048, 256, 0, stream>>>(style, fcw, fcb, mod);
    k_wprep <<<1024, 256, 0, stream>>>(weight, wtb, wsq);
    k_demod <<<2048, 256, 0, stream>>>(mod, wsq, demod);
    k_conv  <<<512,  256, 0, stream>>>(x, mod, wtb, demod, out);
}